// Round 1
// baseline (2444.912 us; speedup 1.0000x reference)
//
#include <hip/hip_runtime.h>
#include <hip/hip_bf16.h>
#include <hip/hip_fp16.h>

// ---- problem constants ----
#define TOK 8192      // 4*2048 tokens
#define HD 2048       // hidden
#define ID 4096       // intermediate
#define NE 8          // experts
#define NPAIR (TOK*2) // token-expert pairs (TOPK=2)
#define BM 128
#define MAXMT (NPAIR/BM + NE)   // 136 worst-case M-tiles
#define PPAD (NPAIR + NE*BM)    // 17408 worst-case padded rows

typedef unsigned short u16;
typedef unsigned int u32;
typedef __attribute__((ext_vector_type(4))) float f32x4;
typedef __attribute__((ext_vector_type(4))) int   i32x4;
typedef u16 u16x8 __attribute__((ext_vector_type(8)));

__device__ __forceinline__ u16 f2h(float f) {
    __half h = __float2half_rn(f);
    return *reinterpret_cast<u16*>(&h);
}

// ---------------- cast x fp32 -> fp16 ----------------
__global__ void cast_x_kernel(const float* __restrict__ x, u16* __restrict__ xh) {
    size_t idx = (size_t)blockIdx.x * 256 + threadIdx.x;   // 8 elems each
    const f32x4* p = (const f32x4*)x + idx * 2;
    f32x4 a = p[0], b = p[1];
    u16x8 o;
#pragma unroll
    for (int i = 0; i < 4; ++i) { o[i] = f2h(a[i]); o[4 + i] = f2h(b[i]); }
    *((u16x8*)xh + idx) = o;
}

// ---------------- router: fp32 logits, softcap, softmax, top2 ----------------
__global__ void router_kernel(const float* __restrict__ x, const float* __restrict__ wg,
                              int* __restrict__ top_e, float* __restrict__ top_w,
                              int* __restrict__ counts) {
    int t = blockIdx.x * 4 + (threadIdx.x >> 6);
    int l = threadIdx.x & 63;
    const float* xr = x + (size_t)t * HD;
    float acc[NE];
#pragma unroll
    for (int e = 0; e < NE; ++e) acc[e] = 0.f;
    for (int h0 = 0; h0 < HD; h0 += 64) {
        int h = h0 + l;
        float xv = xr[h];
        const f32x4* wr = (const f32x4*)(wg + (size_t)h * NE);
        f32x4 w0 = wr[0], w1v = wr[1];
#pragma unroll
        for (int i = 0; i < 4; ++i) { acc[i] += xv * w0[i]; acc[4 + i] += xv * w1v[i]; }
    }
#pragma unroll
    for (int e = 0; e < NE; ++e) {
        float v = acc[e];
        for (int s = 32; s >= 1; s >>= 1) v += __shfl_xor(v, s);
        acc[e] = v;
    }
    if (l == 0) {
        float li[NE], mx = -1e30f;
#pragma unroll
        for (int e = 0; e < NE; ++e) { li[e] = 30.f * tanhf(acc[e] * (1.f / 30.f)); mx = fmaxf(mx, li[e]); }
        float p[NE], se = 0.f;
#pragma unroll
        for (int e = 0; e < NE; ++e) { p[e] = expf(li[e] - mx); se += p[e]; }
        float inv = 1.f / se;
        int i1 = 0; float p1 = p[0];
#pragma unroll
        for (int e = 1; e < NE; ++e) if (p[e] > p1) { p1 = p[e]; i1 = e; }
        int i2 = -1; float p2 = -1e30f;
#pragma unroll
        for (int e = 0; e < NE; ++e) if (e != i1 && p[e] > p2) { p2 = p[e]; i2 = e; }
        top_e[t * 2] = i1; top_e[t * 2 + 1] = i2;
        top_w[t * 2] = p1 * inv; top_w[t * 2 + 1] = p2 * inv;
        atomicAdd(&counts[i1], 1); atomicAdd(&counts[i2], 1);
    }
}

// ---------------- offsets + M-tile table (1 thread) ----------------
__global__ void offsets_kernel(const int* __restrict__ counts, int* __restrict__ offs,
                               int* __restrict__ mt_e, int* __restrict__ mt_r0,
                               int* __restrict__ nmt) {
    if (threadIdx.x != 0) return;
    int off = 0, n = 0;
    for (int e = 0; e < NE; ++e) {
        offs[e] = off;
        int c = counts[e];
        int nt = (c + BM - 1) >> 7;
        for (int j = 0; j < nt; ++j) { mt_e[n] = e; mt_r0[n] = off + j * BM; ++n; }
        off += nt * BM;
    }
    offs[NE] = off;
    *nmt = n;
}

// ---------------- deterministic per-expert compaction ----------------
__global__ void scatter_kernel(const int* __restrict__ top_e, const float* __restrict__ top_w,
                               const int* __restrict__ counts, const int* __restrict__ offs,
                               int* __restrict__ pair_token, float* __restrict__ pair_w) {
    const int e = blockIdx.x;
    const int tid = threadIdx.x;
    __shared__ int sc[256];
    int base = offs[e];
    for (int start = 0; start < TOK; start += 256) {
        int tk = start + tid;
        int m = 0; float w = 0.f;
        int e0 = top_e[tk * 2], e1 = top_e[tk * 2 + 1];
        if (e0 == e) { m = 1; w = top_w[tk * 2]; }
        else if (e1 == e) { m = 1; w = top_w[tk * 2 + 1]; }
        sc[tid] = m;
        __syncthreads();
        for (int s = 1; s < 256; s <<= 1) {
            int v = (tid >= s) ? sc[tid - s] : 0;
            __syncthreads();
            sc[tid] += v;
            __syncthreads();
        }
        if (m) { int pos = base + sc[tid] - 1; pair_token[pos] = tk; pair_w[pos] = w; }
        base += sc[255];
        __syncthreads();
    }
    int cnt = counts[e];
    int padded = (cnt + BM - 1) & ~(BM - 1);
    for (int r = cnt + tid; r < padded; r += 256) {
        pair_token[offs[e] + r] = 0;
        pair_w[offs[e] + r] = 0.f;
    }
}

// ---------------- GEMM1: h = silu(x@w1) * (x@w3), grouped, fp16 MFMA ----------------
// A: gathered x rows (fp16, global_load_lds w/ XOR-swizzled source)
// B: w1/w3 [K=H][N=I] fp32 -> fp16 reg-staged transposed into LDS [N=128][Kpad=72]
__global__ __launch_bounds__(256, 2) void gemm1_kernel(
    const u16* __restrict__ xh, const float* __restrict__ w1, const float* __restrict__ w3,
    const int* __restrict__ pair_token, const int* __restrict__ mt_e, const int* __restrict__ mt_r0,
    const int* __restrict__ nmt, u16* __restrict__ hb) {
    if ((int)blockIdx.x >= *nmt) return;
    const int e = mt_e[blockIdx.x], row0 = mt_r0[blockIdx.x];
    const int bn = blockIdx.y * 128;
    const int tid = threadIdx.x, lane = tid & 63, wv = tid >> 6;
    const int wm = wv >> 1, wn = wv & 1;

    __shared__ u16 sA[128 * 64];
    __shared__ u16 sB1[128 * 72];
    __shared__ u16 sB3[128 * 72];

    // A staging: issue i stages rows r = i*32 + (tid>>3), 16B per thread, source pre-swizzled
    const u16* asrc[4];
#pragma unroll
    for (int i = 0; i < 4; ++i) {
        int r = i * 32 + (tid >> 3);
        int kb = (tid & 7) * 16;
        int kbs = kb ^ ((r & 7) << 4);
        asrc[i] = xh + (size_t)pair_token[row0 + r] * HD + (kbs >> 1);
    }
    const int hp = tid >> 3, ng = tid & 7;      // B staging: h-pair 2hp,2hp+1; n-chunk 16*ng
    const float* p1 = w1 + (size_t)e * HD * ID + (size_t)(2 * hp) * ID + bn + 16 * ng;
    const float* p3 = w3 + (size_t)e * HD * ID + (size_t)(2 * hp) * ID + bn + 16 * ng;
    const size_t wstep = (size_t)64 * ID;

    f32x4 accG[4][4], accU[4][4];
#pragma unroll
    for (int a = 0; a < 4; ++a)
#pragma unroll
        for (int b = 0; b < 4; ++b) { accG[a][b] = (f32x4)0.f; accU[a][b] = (f32x4)0.f; }

    for (int kt = 0; kt < HD / 64; ++kt) {
#pragma unroll
        for (int i = 0; i < 4; ++i) {
            __builtin_amdgcn_global_load_lds(
                (const __attribute__((address_space(1))) void*)asrc[i],
                (__attribute__((address_space(3))) void*)(sA + i * 2048 + wv * 512), 16, 0, 0);
            asrc[i] += 64;
        }
        // B1 staging (rotated q order for bank spread)
#pragma unroll
        for (int q = 0; q < 4; ++q) {
            int qq = (q + ng) & 3;
            const float* pa = p1 + 4 * qq;
            f32x4 va = *(const f32x4*)pa;
            f32x4 vb = *(const f32x4*)(pa + ID);
            int nb = 16 * ng + 4 * qq;
#pragma unroll
            for (int i = 0; i < 4; ++i) {
                u32 pk = (u32)f2h(va[i]) | ((u32)f2h(vb[i]) << 16);
                *(u32*)&sB1[(nb + i) * 72 + 2 * hp] = pk;
            }
        }
#pragma unroll
        for (int q = 0; q < 4; ++q) {
            int qq = (q + ng) & 3;
            const float* pa = p3 + 4 * qq;
            f32x4 va = *(const f32x4*)pa;
            f32x4 vb = *(const f32x4*)(pa + ID);
            int nb = 16 * ng + 4 * qq;
#pragma unroll
            for (int i = 0; i < 4; ++i) {
                u32 pk = (u32)f2h(va[i]) | ((u32)f2h(vb[i]) << 16);
                *(u32*)&sB3[(nb + i) * 72 + 2 * hp] = pk;
            }
        }
        p1 += wstep; p3 += wstep;
        __syncthreads();

#pragma unroll
        for (int ks = 0; ks < 2; ++ks) {
            i32x4 a[4];
#pragma unroll
            for (int mf = 0; mf < 4; ++mf) {
                int r = wm * 64 + mf * 16 + (lane & 15);
                int lb = (((lane >> 4) * 16) + ks * 64) ^ ((r & 7) << 4);
                a[mf] = *(const i32x4*)((const char*)sA + (size_t)r * 128 + lb);
            }
#pragma unroll
            for (int nf = 0; nf < 4; ++nf) {
                int n = wn * 64 + nf * 16 + (lane & 15);
                int kk = ks * 32 + (lane >> 4) * 8;
                i32x4 b1 = *(const i32x4*)&sB1[n * 72 + kk];
                i32x4 b3 = *(const i32x4*)&sB3[n * 72 + kk];
#pragma unroll
                for (int mf = 0; mf < 4; ++mf) {
                    asm("v_mfma_f32_16x16x32_f16 %0, %1, %2, %0" : "+v"(accG[mf][nf]) : "v"(a[mf]), "v"(b1));
                    asm("v_mfma_f32_16x16x32_f16 %0, %1, %2, %0" : "+v"(accU[mf][nf]) : "v"(a[mf]), "v"(b3));
                }
            }
        }
        __syncthreads();
    }

    // epilogue: silu(g)*u -> fp16 h
#pragma unroll
    for (int mf = 0; mf < 4; ++mf) {
#pragma unroll
        for (int j = 0; j < 4; ++j) {
            size_t r = (size_t)row0 + wm * 64 + mf * 16 + (lane >> 4) * 4 + j;
            u16* hp_ = hb + r * ID + bn + wn * 64 + (lane & 15);
#pragma unroll
            for (int nf = 0; nf < 4; ++nf) {
                float g = accG[mf][nf][j], u = accU[mf][nf][j];
                float s = g / (1.f + expf(-g));
                hp_[nf * 16] = f2h(s * u);
            }
        }
    }
}

// ---------------- GEMM2: out += (h@w2) * weight (atomicAdd fp32) ----------------
__global__ __launch_bounds__(256, 2) void gemm2_kernel(
    const u16* __restrict__ hb, const float* __restrict__ w2,
    const int* __restrict__ pair_token, const float* __restrict__ pair_w,
    const int* __restrict__ mt_e, const int* __restrict__ mt_r0, const int* __restrict__ nmt,
    float* __restrict__ out) {
    if ((int)blockIdx.x >= *nmt) return;
    const int e = mt_e[blockIdx.x], row0 = mt_r0[blockIdx.x];
    const int bn = blockIdx.y * 128;
    const int tid = threadIdx.x, lane = tid & 63, wv = tid >> 6;
    const int wm = wv >> 1, wn = wv & 1;

    __shared__ u16 sA[128 * 64];
    __shared__ u16 sB[128 * 72];

    const u16* asrc[4];
#pragma unroll
    for (int i = 0; i < 4; ++i) {
        int r = i * 32 + (tid >> 3);
        int kb = (tid & 7) * 16;
        int kbs = kb ^ ((r & 7) << 4);
        asrc[i] = hb + (size_t)(row0 + r) * ID + (kbs >> 1);
    }
    const int hp = tid >> 3, ng = tid & 7;
    const float* pb = w2 + (size_t)e * ID * HD + (size_t)(2 * hp) * HD + bn + 16 * ng;
    const size_t wstep = (size_t)64 * HD;

    f32x4 acc[4][4];
#pragma unroll
    for (int a = 0; a < 4; ++a)
#pragma unroll
        for (int b = 0; b < 4; ++b) acc[a][b] = (f32x4)0.f;

    for (int kt = 0; kt < ID / 64; ++kt) {
#pragma unroll
        for (int i = 0; i < 4; ++i) {
            __builtin_amdgcn_global_load_lds(
                (const __attribute__((address_space(1))) void*)asrc[i],
                (__attribute__((address_space(3))) void*)(sA + i * 2048 + wv * 512), 16, 0, 0);
            asrc[i] += 64;
        }
#pragma unroll
        for (int q = 0; q < 4; ++q) {
            int qq = (q + ng) & 3;
            const float* pa = pb + 4 * qq;
            f32x4 va = *(const f32x4*)pa;
            f32x4 vb = *(const f32x4*)(pa + HD);
            int nb = 16 * ng + 4 * qq;
#pragma unroll
            for (int i = 0; i < 4; ++i) {
                u32 pk = (u32)f2h(va[i]) | ((u32)f2h(vb[i]) << 16);
                *(u32*)&sB[(nb + i) * 72 + 2 * hp] = pk;
            }
        }
        pb += wstep;
        __syncthreads();

#pragma unroll
        for (int ks = 0; ks < 2; ++ks) {
            i32x4 a[4];
#pragma unroll
            for (int mf = 0; mf < 4; ++mf) {
                int r = wm * 64 + mf * 16 + (lane & 15);
                int lb = (((lane >> 4) * 16) + ks * 64) ^ ((r & 7) << 4);
                a[mf] = *(const i32x4*)((const char*)sA + (size_t)r * 128 + lb);
            }
#pragma unroll
            for (int nf = 0; nf < 4; ++nf) {
                int n = wn * 64 + nf * 16 + (lane & 15);
                int kk = ks * 32 + (lane >> 4) * 8;
                i32x4 b = *(const i32x4*)&sB[n * 72 + kk];
#pragma unroll
                for (int mf = 0; mf < 4; ++mf) {
                    asm("v_mfma_f32_16x16x32_f16 %0, %1, %2, %0" : "+v"(acc[mf][nf]) : "v"(a[mf]), "v"(b));
                }
            }
        }
        __syncthreads();
    }

#pragma unroll
    for (int mf = 0; mf < 4; ++mf) {
#pragma unroll
        for (int j = 0; j < 4; ++j) {
            int rr = row0 + wm * 64 + mf * 16 + (lane >> 4) * 4 + j;
            int tok = pair_token[rr];
            float wt = pair_w[rr];
            float* op = out + (size_t)tok * HD + bn + wn * 64 + (lane & 15);
#pragma unroll
            for (int nf = 0; nf < 4; ++nf) {
                atomicAdd(op + nf * 16, acc[mf][nf][j] * wt);
            }
        }
    }
}

extern "C" void kernel_launch(void* const* d_in, const int* in_sizes, int n_in,
                              void* d_out, int out_size, void* d_ws, size_t ws_size,
                              hipStream_t stream) {
    (void)in_sizes; (void)n_in; (void)ws_size;
    const float* x  = (const float*)d_in[0];
    const float* wg = (const float*)d_in[1];
    const float* w1 = (const float*)d_in[2];
    const float* w3 = (const float*)d_in[3];
    const float* w2 = (const float*)d_in[4];
    float* out = (float*)d_out;

    char* ws = (char*)d_ws;
    size_t off = 0;
    auto alloc = [&](size_t bytes) -> void* {
        void* p = ws + off;
        off = (off + bytes + 255) & ~(size_t)255;
        return p;
    };
    u16* xh          = (u16*)alloc((size_t)TOK * HD * 2);
    u16* hb          = (u16*)alloc((size_t)PPAD * ID * 2);
    int* pair_token  = (int*)alloc((size_t)PPAD * 4);
    float* pair_w    = (float*)alloc((size_t)PPAD * 4);
    int* top_e       = (int*)alloc((size_t)TOK * 2 * 4);
    float* top_w     = (float*)alloc((size_t)TOK * 2 * 4);
    int* counts      = (int*)alloc(64);
    int* offs        = (int*)alloc(64);
    int* mt_e        = (int*)alloc((size_t)MAXMT * 4);
    int* mt_r0       = (int*)alloc((size_t)MAXMT * 4);
    int* nmt         = (int*)alloc(64);

    hipMemsetAsync(out, 0, (size_t)out_size * 4, stream);
    hipMemsetAsync(counts, 0, 64, stream);

    cast_x_kernel<<<TOK * HD / 8 / 256, 256, 0, stream>>>(x, xh);
    router_kernel<<<TOK / 4, 256, 0, stream>>>(x, wg, top_e, top_w, counts);
    offsets_kernel<<<1, 64, 0, stream>>>(counts, offs, mt_e, mt_r0, nmt);
    scatter_kernel<<<NE, 256, 0, stream>>>(top_e, top_w, counts, offs, pair_token, pair_w);
    gemm1_kernel<<<dim3(MAXMT, ID / 128), 256, 0, stream>>>(xh, w1, w3, pair_token, mt_e, mt_r0, nmt, hb);
    gemm2_kernel<<<dim3(MAXMT, HD / 128), 256, 0, stream>>>(hb, w2, pair_token, pair_w, mt_e, mt_r0, nmt, out);
}

// Round 2
// 1893.519 us; speedup vs baseline: 1.2912x; 1.2912x over previous
//
#include <hip/hip_runtime.h>
#include <hip/hip_bf16.h>
#include <hip/hip_fp16.h>

// ---- problem constants ----
#define TOK 8192      // 4*2048 tokens
#define HD 2048       // hidden
#define ID 4096       // intermediate
#define NE 8          // experts
#define NPAIR (TOK*2) // token-expert pairs (TOPK=2)
#define BM 128
#define MAXMT (NPAIR/BM + NE)   // 136 worst-case M-tiles
#define PPAD (NPAIR + NE*BM)    // 17408 worst-case padded rows

typedef unsigned short u16;
typedef unsigned int u32;
typedef __attribute__((ext_vector_type(4))) float f32x4;
typedef __attribute__((ext_vector_type(4))) int   i32x4;
typedef u16 u16x8 __attribute__((ext_vector_type(8)));
typedef u16 u16x4 __attribute__((ext_vector_type(4)));

__device__ __forceinline__ u16 f2h(float f) {
    __half h = __float2half_rn(f);
    return *reinterpret_cast<u16*>(&h);
}

// ---------------- cast x fp32 -> fp16 ----------------
__global__ void cast_x_kernel(const float* __restrict__ x, u16* __restrict__ xh) {
    size_t idx = (size_t)blockIdx.x * 256 + threadIdx.x;   // 8 elems each
    const f32x4* p = (const f32x4*)x + idx * 2;
    f32x4 a = p[0], b = p[1];
    u16x8 o;
#pragma unroll
    for (int i = 0; i < 4; ++i) { o[i] = f2h(a[i]); o[4 + i] = f2h(b[i]); }
    *((u16x8*)xh + idx) = o;
}

// ---------------- prep: w1/w3 fp32 [H][I] -> interleaved fp16 wcat [2*I][H] ----------------
// wcat row for w1 col n: ((n>>4)<<5)|(n&15);  for w3: ((n>>4)<<5)|16|(n&15)
__global__ __launch_bounds__(256) void prep_w13_kernel(const float* __restrict__ w1,
                                                       const float* __restrict__ w3,
                                                       u16* __restrict__ wcat) {
    __shared__ u16 tile[64][68];   // [n_local][k_local], pad 68 -> 2-way write conflicts only
    const int k0 = blockIdx.x * 64, n0 = blockIdx.y * 64;
    const int e = blockIdx.z >> 1, which = blockIdx.z & 1;
    const float* src = (which ? w3 : w1) + (size_t)e * HD * ID;
    u16* dst = wcat + (size_t)e * 2 * ID * HD;
    const int tid = threadIdx.x, r = tid >> 4, c4 = (tid & 15) * 4;
#pragma unroll
    for (int i = 0; i < 4; ++i) {
        int k = k0 + r + 16 * i;
        f32x4 v = *(const f32x4*)(src + (size_t)k * ID + n0 + c4);
#pragma unroll
        for (int j = 0; j < 4; ++j) tile[c4 + j][r + 16 * i] = f2h(v[j]);
    }
    __syncthreads();
#pragma unroll
    for (int i = 0; i < 4; ++i) {
        int nl = r + 16 * i;
        int n = n0 + nl;
        int wr = ((n >> 4) << 5) | (which << 4) | (n & 15);
        u16x4 o;
#pragma unroll
        for (int j = 0; j < 4; ++j) o[j] = tile[nl][c4 + j];
        *(u16x4*)(dst + (size_t)wr * HD + k0 + c4) = o;
    }
}

// ---------------- prep: w2 fp32 [I][H] -> fp16 w2t [H][I] ----------------
__global__ __launch_bounds__(256) void prep_w2_kernel(const float* __restrict__ w2,
                                                      u16* __restrict__ w2t) {
    __shared__ u16 tile[64][68];
    const int k0 = blockIdx.x * 64, n0 = blockIdx.y * 64;
    const int e = blockIdx.z;
    const float* src = w2 + (size_t)e * ID * HD;
    u16* dst = w2t + (size_t)e * ID * HD;
    const int tid = threadIdx.x, r = tid >> 4, c4 = (tid & 15) * 4;
#pragma unroll
    for (int i = 0; i < 4; ++i) {
        int k = k0 + r + 16 * i;
        f32x4 v = *(const f32x4*)(src + (size_t)k * HD + n0 + c4);
#pragma unroll
        for (int j = 0; j < 4; ++j) tile[c4 + j][r + 16 * i] = f2h(v[j]);
    }
    __syncthreads();
#pragma unroll
    for (int i = 0; i < 4; ++i) {
        int nl = r + 16 * i;
        u16x4 o;
#pragma unroll
        for (int j = 0; j < 4; ++j) o[j] = tile[nl][c4 + j];
        *(u16x4*)(dst + (size_t)(n0 + nl) * ID + k0 + c4) = o;
    }
}

// ---------------- router: fp32 logits, softcap, softmax, top2 ----------------
__global__ void router_kernel(const float* __restrict__ x, const float* __restrict__ wg,
                              int* __restrict__ top_e, float* __restrict__ top_w,
                              int* __restrict__ counts) {
    int t = blockIdx.x * 4 + (threadIdx.x >> 6);
    int l = threadIdx.x & 63;
    const float* xr = x + (size_t)t * HD;
    float acc[NE];
#pragma unroll
    for (int e = 0; e < NE; ++e) acc[e] = 0.f;
    for (int h0 = 0; h0 < HD; h0 += 64) {
        int h = h0 + l;
        float xv = xr[h];
        const f32x4* wr = (const f32x4*)(wg + (size_t)h * NE);
        f32x4 w0 = wr[0], w1v = wr[1];
#pragma unroll
        for (int i = 0; i < 4; ++i) { acc[i] += xv * w0[i]; acc[4 + i] += xv * w1v[i]; }
    }
#pragma unroll
    for (int e = 0; e < NE; ++e) {
        float v = acc[e];
        for (int s = 32; s >= 1; s >>= 1) v += __shfl_xor(v, s);
        acc[e] = v;
    }
    if (l == 0) {
        float li[NE], mx = -1e30f;
#pragma unroll
        for (int e = 0; e < NE; ++e) { li[e] = 30.f * tanhf(acc[e] * (1.f / 30.f)); mx = fmaxf(mx, li[e]); }
        float p[NE], se = 0.f;
#pragma unroll
        for (int e = 0; e < NE; ++e) { p[e] = expf(li[e] - mx); se += p[e]; }
        float inv = 1.f / se;
        int i1 = 0; float p1 = p[0];
#pragma unroll
        for (int e = 1; e < NE; ++e) if (p[e] > p1) { p1 = p[e]; i1 = e; }
        int i2 = -1; float p2 = -1e30f;
#pragma unroll
        for (int e = 0; e < NE; ++e) if (e != i1 && p[e] > p2) { p2 = p[e]; i2 = e; }
        top_e[t * 2] = i1; top_e[t * 2 + 1] = i2;
        top_w[t * 2] = p1 * inv; top_w[t * 2 + 1] = p2 * inv;
        atomicAdd(&counts[i1], 1); atomicAdd(&counts[i2], 1);
    }
}

// ---------------- offsets + M-tile table (1 thread) ----------------
__global__ void offsets_kernel(const int* __restrict__ counts, int* __restrict__ offs,
                               int* __restrict__ mt_e, int* __restrict__ mt_r0,
                               int* __restrict__ nmt) {
    if (threadIdx.x != 0) return;
    int off = 0, n = 0;
    for (int e = 0; e < NE; ++e) {
        offs[e] = off;
        int c = counts[e];
        int nt = (c + BM - 1) >> 7;
        for (int j = 0; j < nt; ++j) { mt_e[n] = e; mt_r0[n] = off + j * BM; ++n; }
        off += nt * BM;
    }
    offs[NE] = off;
    *nmt = n;
}

// ---------------- deterministic per-expert compaction ----------------
__global__ void scatter_kernel(const int* __restrict__ top_e, const float* __restrict__ top_w,
                               const int* __restrict__ counts, const int* __restrict__ offs,
                               int* __restrict__ pair_token, float* __restrict__ pair_w) {
    const int e = blockIdx.x;
    const int tid = threadIdx.x;
    __shared__ int sc[256];
    int base = offs[e];
    for (int start = 0; start < TOK; start += 256) {
        int tk = start + tid;
        int m = 0; float w = 0.f;
        int e0 = top_e[tk * 2], e1 = top_e[tk * 2 + 1];
        if (e0 == e) { m = 1; w = top_w[tk * 2]; }
        else if (e1 == e) { m = 1; w = top_w[tk * 2 + 1]; }
        sc[tid] = m;
        __syncthreads();
        for (int s = 1; s < 256; s <<= 1) {
            int v = (tid >= s) ? sc[tid - s] : 0;
            __syncthreads();
            sc[tid] += v;
            __syncthreads();
        }
        if (m) { int pos = base + sc[tid] - 1; pair_token[pos] = tk; pair_w[pos] = w; }
        base += sc[255];
        __syncthreads();
    }
    int cnt = counts[e];
    int padded = (cnt + BM - 1) & ~(BM - 1);
    for (int r = cnt + tid; r < padded; r += 256) {
        pair_token[offs[e] + r] = 0;
        pair_w[offs[e] + r] = 0.f;
    }
}

// ---------------- GEMM1: h = silu(x@w1) * (x@w3), m97 structure, fp16 MFMA ----------------
// A: gathered xh rows; B: wcat rows (g/u interleaved at 16-col granularity).
// Both staged via global_load_lds width-16 with pre-swizzled sources.
__global__ __launch_bounds__(256, 3) void gemm1_kernel(
    const u16* __restrict__ xh, const u16* __restrict__ wcat,
    const int* __restrict__ pair_token, const int* __restrict__ mt_e,
    const int* __restrict__ mt_r0, const int* __restrict__ nmt,
    u16* __restrict__ hb) {
    if ((int)blockIdx.x >= *nmt) return;
    const int e = mt_e[blockIdx.x], row0 = mt_r0[blockIdx.x];
    const int by = blockIdx.y;
    const int tid = threadIdx.x, lane = tid & 63, wv = tid >> 6;
    const int wm = wv >> 1, wn = wv & 1;

    __shared__ u16 sA[128 * 64];
    __shared__ u16 sB[128 * 64];

    const u16* asrc[4];
    const u16* bsrc[4];
#pragma unroll
    for (int i = 0; i < 4; ++i) {
        int rl = i * 32 + (tid >> 3);
        int kbs = ((tid & 7) * 16) ^ ((rl & 7) << 4);      // byte offset, pre-swizzled
        asrc[i] = xh + (size_t)pair_token[row0 + rl] * HD + (kbs >> 1);
        bsrc[i] = wcat + (size_t)e * 2 * ID * HD + (size_t)(by * 128 + rl) * HD + (kbs >> 1);
    }

    f32x4 acc[4][4];
#pragma unroll
    for (int a = 0; a < 4; ++a)
#pragma unroll
        for (int b = 0; b < 4; ++b) acc[a][b] = (f32x4)0.f;

    for (int kt = 0; kt < HD / 64; ++kt) {
#pragma unroll
        for (int i = 0; i < 4; ++i) {
            __builtin_amdgcn_global_load_lds(
                (const __attribute__((address_space(1))) void*)asrc[i],
                (__attribute__((address_space(3))) void*)(sA + i * 2048 + wv * 512), 16, 0, 0);
            asrc[i] += 64;
        }
#pragma unroll
        for (int i = 0; i < 4; ++i) {
            __builtin_amdgcn_global_load_lds(
                (const __attribute__((address_space(1))) void*)bsrc[i],
                (__attribute__((address_space(3))) void*)(sB + i * 2048 + wv * 512), 16, 0, 0);
            bsrc[i] += 64;
        }
        __syncthreads();
#pragma unroll
        for (int ks = 0; ks < 2; ++ks) {
            i32x4 a[4], b[4];
#pragma unroll
            for (int mf = 0; mf < 4; ++mf) {
                int rr = wm * 64 + mf * 16 + (lane & 15);
                int lb = ((lane >> 4) * 16 + ks * 64) ^ ((rr & 7) << 4);
                a[mf] = *(const i32x4*)((const char*)sA + rr * 128 + lb);
            }
#pragma unroll
            for (int nf = 0; nf < 4; ++nf) {
                int nn = wn * 64 + nf * 16 + (lane & 15);
                int lb = ((lane >> 4) * 16 + ks * 64) ^ ((nn & 7) << 4);
                b[nf] = *(const i32x4*)((const char*)sB + nn * 128 + lb);
            }
#pragma unroll
            for (int nf = 0; nf < 4; ++nf)
#pragma unroll
                for (int mf = 0; mf < 4; ++mf)
                    asm("v_mfma_f32_16x16x32_f16 %0, %1, %2, %0" : "+v"(acc[mf][nf]) : "v"(a[mf]), "v"(b[nf]));
        }
        __syncthreads();
    }

    // epilogue: nf even = gate, nf odd = up; real col = by*64 + wn*32 + np*16 + (lane&15)
#pragma unroll
    for (int mf = 0; mf < 4; ++mf) {
#pragma unroll
        for (int j = 0; j < 4; ++j) {
            size_t rr = (size_t)row0 + wm * 64 + mf * 16 + (lane >> 4) * 4 + j;
            u16* hp_ = hb + rr * ID + by * 64 + wn * 32 + (lane & 15);
#pragma unroll
            for (int np = 0; np < 2; ++np) {
                float g = acc[mf][2 * np][j], u = acc[mf][2 * np + 1][j];
                float s = g / (1.f + expf(-g));
                hp_[np * 16] = f2h(s * u);
            }
        }
    }
}

// ---------------- GEMM2: out += (h@w2t) * weight (atomicAdd fp32) ----------------
__global__ __launch_bounds__(256, 3) void gemm2_kernel(
    const u16* __restrict__ hb, const u16* __restrict__ w2t,
    const int* __restrict__ pair_token, const float* __restrict__ pair_w,
    const int* __restrict__ mt_e, const int* __restrict__ mt_r0, const int* __restrict__ nmt,
    float* __restrict__ out) {
    if ((int)blockIdx.x >= *nmt) return;
    const int e = mt_e[blockIdx.x], row0 = mt_r0[blockIdx.x];
    const int by = blockIdx.y;
    const int tid = threadIdx.x, lane = tid & 63, wv = tid >> 6;
    const int wm = wv >> 1, wn = wv & 1;

    __shared__ u16 sA[128 * 64];
    __shared__ u16 sB[128 * 64];

    const u16* asrc[4];
    const u16* bsrc[4];
#pragma unroll
    for (int i = 0; i < 4; ++i) {
        int rl = i * 32 + (tid >> 3);
        int kbs = ((tid & 7) * 16) ^ ((rl & 7) << 4);
        asrc[i] = hb + (size_t)(row0 + rl) * ID + (kbs >> 1);
        bsrc[i] = w2t + (size_t)e * HD * ID + (size_t)(by * 128 + rl) * ID + (kbs >> 1);
    }

    f32x4 acc[4][4];
#pragma unroll
    for (int a = 0; a < 4; ++a)
#pragma unroll
        for (int b = 0; b < 4; ++b) acc[a][b] = (f32x4)0.f;

    for (int kt = 0; kt < ID / 64; ++kt) {
#pragma unroll
        for (int i = 0; i < 4; ++i) {
            __builtin_amdgcn_global_load_lds(
                (const __attribute__((address_space(1))) void*)asrc[i],
                (__attribute__((address_space(3))) void*)(sA + i * 2048 + wv * 512), 16, 0, 0);
            asrc[i] += 64;
        }
#pragma unroll
        for (int i = 0; i < 4; ++i) {
            __builtin_amdgcn_global_load_lds(
                (const __attribute__((address_space(1))) void*)bsrc[i],
                (__attribute__((address_space(3))) void*)(sB + i * 2048 + wv * 512), 16, 0, 0);
            bsrc[i] += 64;
        }
        __syncthreads();
#pragma unroll
        for (int ks = 0; ks < 2; ++ks) {
            i32x4 a[4], b[4];
#pragma unroll
            for (int mf = 0; mf < 4; ++mf) {
                int rr = wm * 64 + mf * 16 + (lane & 15);
                int lb = ((lane >> 4) * 16 + ks * 64) ^ ((rr & 7) << 4);
                a[mf] = *(const i32x4*)((const char*)sA + rr * 128 + lb);
            }
#pragma unroll
            for (int nf = 0; nf < 4; ++nf) {
                int nn = wn * 64 + nf * 16 + (lane & 15);
                int lb = ((lane >> 4) * 16 + ks * 64) ^ ((nn & 7) << 4);
                b[nf] = *(const i32x4*)((const char*)sB + nn * 128 + lb);
            }
#pragma unroll
            for (int nf = 0; nf < 4; ++nf)
#pragma unroll
                for (int mf = 0; mf < 4; ++mf)
                    asm("v_mfma_f32_16x16x32_f16 %0, %1, %2, %0" : "+v"(acc[mf][nf]) : "v"(a[mf]), "v"(b[nf]));
        }
        __syncthreads();
    }

#pragma unroll
    for (int mf = 0; mf < 4; ++mf) {
#pragma unroll
        for (int j = 0; j < 4; ++j) {
            int rr = row0 + wm * 64 + mf * 16 + (lane >> 4) * 4 + j;
            int tok = pair_token[rr];
            float wt = pair_w[rr];
            float* op = out + (size_t)tok * HD + by * 128 + wn * 64 + (lane & 15);
#pragma unroll
            for (int nf = 0; nf < 4; ++nf) {
                atomicAdd(op + nf * 16, acc[mf][nf][j] * wt);
            }
        }
    }
}

extern "C" void kernel_launch(void* const* d_in, const int* in_sizes, int n_in,
                              void* d_out, int out_size, void* d_ws, size_t ws_size,
                              hipStream_t stream) {
    (void)in_sizes; (void)n_in; (void)ws_size;
    const float* x  = (const float*)d_in[0];
    const float* wg = (const float*)d_in[1];
    const float* w1 = (const float*)d_in[2];
    const float* w3 = (const float*)d_in[3];
    const float* w2 = (const float*)d_in[4];
    float* out = (float*)d_out;

    char* ws = (char*)d_ws;
    size_t off = 0;
    auto alloc = [&](size_t bytes) -> void* {
        void* p = ws + off;
        off = (off + bytes + 255) & ~(size_t)255;
        return p;
    };
    u16* xh          = (u16*)alloc((size_t)TOK * HD * 2);
    u16* hb          = (u16*)alloc((size_t)PPAD * ID * 2);
    u16* wcat        = (u16*)alloc((size_t)NE * 2 * ID * HD * 2);  // w13 interleaved fp16
    u16* w2t         = wcat;                                       // aliased: used after gemm1
    int* pair_token  = (int*)alloc((size_t)PPAD * 4);
    float* pair_w    = (float*)alloc((size_t)PPAD * 4);
    int* top_e       = (int*)alloc((size_t)TOK * 2 * 4);
    float* top_w     = (float*)alloc((size_t)TOK * 2 * 4);
    int* counts      = (int*)alloc(64);
    int* offs        = (int*)alloc(64);
    int* mt_e        = (int*)alloc((size_t)MAXMT * 4);
    int* mt_r0       = (int*)alloc((size_t)MAXMT * 4);
    int* nmt         = (int*)alloc(64);

    hipMemsetAsync(out, 0, (size_t)out_size * 4, stream);
    hipMemsetAsync(counts, 0, 64, stream);

    cast_x_kernel<<<TOK * HD / 8 / 256, 256, 0, stream>>>(x, xh);
    router_kernel<<<TOK / 4, 256, 0, stream>>>(x, wg, top_e, top_w, counts);
    offsets_kernel<<<1, 64, 0, stream>>>(counts, offs, mt_e, mt_r0, nmt);
    scatter_kernel<<<NE, 256, 0, stream>>>(top_e, top_w, counts, offs, pair_token, pair_w);
    prep_w13_kernel<<<dim3(HD / 64, ID / 64, NE * 2), 256, 0, stream>>>(w1, w3, wcat);
    gemm1_kernel<<<dim3(MAXMT, ID / 64), 256, 0, stream>>>(xh, wcat, pair_token, mt_e, mt_r0, nmt, hb);
    prep_w2_kernel<<<dim3(ID / 64, HD / 64, NE), 256, 0, stream>>>(w2, w2t);  // wcat dead now
    gemm2_kernel<<<dim3(MAXMT, HD / 128), 256, 0, stream>>>(hb, w2t, pair_token, pair_w, mt_e, mt_r0, nmt, out);
}

// Round 3
// 1393.779 us; speedup vs baseline: 1.7542x; 1.3586x over previous
//
#include <hip/hip_runtime.h>
#include <hip/hip_bf16.h>
#include <hip/hip_fp16.h>

// ---- problem constants ----
#define TOK 8192      // 4*2048 tokens
#define HD 2048       // hidden
#define ID 4096       // intermediate
#define NE 8          // experts
#define NPAIR (TOK*2) // token-expert pairs (TOPK=2)
#define BM 128
#define MAXMT (NPAIR/BM + NE)   // 136 worst-case M-tiles
#define PPAD (NPAIR + NE*BM)    // 17408 worst-case padded rows

typedef unsigned short u16;
typedef unsigned int u32;
typedef __attribute__((ext_vector_type(4))) float f32x4;
typedef __attribute__((ext_vector_type(4))) int   i32x4;
typedef u16 u16x8 __attribute__((ext_vector_type(8)));
typedef u16 u16x4 __attribute__((ext_vector_type(4)));

__device__ __forceinline__ u16 f2h(float f) {
    __half h = __float2half_rn(f);
    return *reinterpret_cast<u16*>(&h);
}

// XCD-clustered remap: cluster = 8mt x 8by = 64 blocks, all on one XCD
// (p%8 = XCD round-robin). Cluster grid = CGM x CGN, CGM*CGN must be
// divisible by 8. Consecutive cluster ids share the by-range (mtc-major).
__device__ __forceinline__ void xcd_remap(int p, int CGM, int& mt, int& by) {
    int x = p & 7;          // XCD
    int j = p >> 3;         // sequence within XCD
    int c = j >> 6;         // cluster counter within XCD
    int s = j & 63;         // slot within cluster
    int C = c * 8 + x;      // global cluster id
    int mtc = C % CGM;
    int byc = C / CGM;
    mt = mtc * 8 + (s >> 3);
    by = byc * 8 + (s & 7);
}

// ---------------- cast x fp32 -> fp16 ----------------
__global__ void cast_x_kernel(const float* __restrict__ x, u16* __restrict__ xh) {
    size_t idx = (size_t)blockIdx.x * 256 + threadIdx.x;   // 8 elems each
    const f32x4* p = (const f32x4*)x + idx * 2;
    f32x4 a = p[0], b = p[1];
    u16x8 o;
#pragma unroll
    for (int i = 0; i < 4; ++i) { o[i] = f2h(a[i]); o[4 + i] = f2h(b[i]); }
    *((u16x8*)xh + idx) = o;
}

// ---------------- prep: w1/w3 fp32 [H][I] -> interleaved fp16 wcat [2*I][H] ----------------
// wcat row for w1 col n: ((n>>4)<<5)|(n&15);  for w3: ((n>>4)<<5)|16|(n&15)
__global__ __launch_bounds__(256) void prep_w13_kernel(const float* __restrict__ w1,
                                                       const float* __restrict__ w3,
                                                       u16* __restrict__ wcat) {
    __shared__ u16 tile[64][68];   // [n_local][k_local]
    const int k0 = blockIdx.x * 64, n0 = blockIdx.y * 64;
    const int e = blockIdx.z >> 1, which = blockIdx.z & 1;
    const float* src = (which ? w3 : w1) + (size_t)e * HD * ID;
    u16* dst = wcat + (size_t)e * 2 * ID * HD;
    const int tid = threadIdx.x, r = tid >> 4, c4 = (tid & 15) * 4;
#pragma unroll
    for (int i = 0; i < 4; ++i) {
        int k = k0 + r + 16 * i;
        f32x4 v = *(const f32x4*)(src + (size_t)k * ID + n0 + c4);
#pragma unroll
        for (int j = 0; j < 4; ++j) tile[c4 + j][r + 16 * i] = f2h(v[j]);
    }
    __syncthreads();
#pragma unroll
    for (int i = 0; i < 4; ++i) {
        int nl = r + 16 * i;
        int n = n0 + nl;
        int wr = ((n >> 4) << 5) | (which << 4) | (n & 15);
        u16x4 o;
#pragma unroll
        for (int j = 0; j < 4; ++j) o[j] = tile[nl][c4 + j];
        *(u16x4*)(dst + (size_t)wr * HD + k0 + c4) = o;
    }
}

// ---------------- prep: w2 fp32 [I][H] -> fp16 w2t [H][I] ----------------
__global__ __launch_bounds__(256) void prep_w2_kernel(const float* __restrict__ w2,
                                                      u16* __restrict__ w2t) {
    __shared__ u16 tile[64][68];
    const int k0 = blockIdx.x * 64, n0 = blockIdx.y * 64;
    const int e = blockIdx.z;
    const float* src = w2 + (size_t)e * ID * HD;
    u16* dst = w2t + (size_t)e * ID * HD;
    const int tid = threadIdx.x, r = tid >> 4, c4 = (tid & 15) * 4;
#pragma unroll
    for (int i = 0; i < 4; ++i) {
        int k = k0 + r + 16 * i;
        f32x4 v = *(const f32x4*)(src + (size_t)k * HD + n0 + c4);
#pragma unroll
        for (int j = 0; j < 4; ++j) tile[c4 + j][r + 16 * i] = f2h(v[j]);
    }
    __syncthreads();
#pragma unroll
    for (int i = 0; i < 4; ++i) {
        int nl = r + 16 * i;
        u16x4 o;
#pragma unroll
        for (int j = 0; j < 4; ++j) o[j] = tile[nl][c4 + j];
        *(u16x4*)(dst + (size_t)(n0 + nl) * ID + k0 + c4) = o;
    }
}

// ---------------- router: fp32 logits, softcap, softmax, top2 ----------------
__global__ void router_kernel(const float* __restrict__ x, const float* __restrict__ wg,
                              int* __restrict__ top_e, float* __restrict__ top_w,
                              int* __restrict__ counts) {
    int t = blockIdx.x * 4 + (threadIdx.x >> 6);
    int l = threadIdx.x & 63;
    const float* xr = x + (size_t)t * HD;
    float acc[NE];
#pragma unroll
    for (int e = 0; e < NE; ++e) acc[e] = 0.f;
    for (int h0 = 0; h0 < HD; h0 += 64) {
        int h = h0 + l;
        float xv = xr[h];
        const f32x4* wr = (const f32x4*)(wg + (size_t)h * NE);
        f32x4 w0 = wr[0], w1v = wr[1];
#pragma unroll
        for (int i = 0; i < 4; ++i) { acc[i] += xv * w0[i]; acc[4 + i] += xv * w1v[i]; }
    }
#pragma unroll
    for (int e = 0; e < NE; ++e) {
        float v = acc[e];
        for (int s = 32; s >= 1; s >>= 1) v += __shfl_xor(v, s);
        acc[e] = v;
    }
    if (l == 0) {
        float li[NE], mx = -1e30f;
#pragma unroll
        for (int e = 0; e < NE; ++e) { li[e] = 30.f * tanhf(acc[e] * (1.f / 30.f)); mx = fmaxf(mx, li[e]); }
        float p[NE], se = 0.f;
#pragma unroll
        for (int e = 0; e < NE; ++e) { p[e] = expf(li[e] - mx); se += p[e]; }
        float inv = 1.f / se;
        int i1 = 0; float p1 = p[0];
#pragma unroll
        for (int e = 1; e < NE; ++e) if (p[e] > p1) { p1 = p[e]; i1 = e; }
        int i2 = -1; float p2 = -1e30f;
#pragma unroll
        for (int e = 0; e < NE; ++e) if (e != i1 && p[e] > p2) { p2 = p[e]; i2 = e; }
        top_e[t * 2] = i1; top_e[t * 2 + 1] = i2;
        top_w[t * 2] = p1 * inv; top_w[t * 2 + 1] = p2 * inv;
        atomicAdd(&counts[i1], 1); atomicAdd(&counts[i2], 1);
    }
}

// ---------------- offsets + M-tile table (1 thread) ----------------
__global__ void offsets_kernel(const int* __restrict__ counts, int* __restrict__ offs,
                               int* __restrict__ mt_e, int* __restrict__ mt_r0,
                               int* __restrict__ nmt) {
    if (threadIdx.x != 0) return;
    int off = 0, n = 0;
    for (int e = 0; e < NE; ++e) {
        offs[e] = off;
        int c = counts[e];
        int nt = (c + BM - 1) >> 7;
        for (int j = 0; j < nt; ++j) { mt_e[n] = e; mt_r0[n] = off + j * BM; ++n; }
        off += nt * BM;
    }
    offs[NE] = off;
    *nmt = n;
}

// ---------------- deterministic per-expert compaction ----------------
__global__ void scatter_kernel(const int* __restrict__ top_e, const float* __restrict__ top_w,
                               const int* __restrict__ counts, const int* __restrict__ offs,
                               int* __restrict__ pair_token, float* __restrict__ pair_w) {
    const int e = blockIdx.x;
    const int tid = threadIdx.x;
    __shared__ int sc[256];
    int base = offs[e];
    for (int start = 0; start < TOK; start += 256) {
        int tk = start + tid;
        int m = 0; float w = 0.f;
        int e0 = top_e[tk * 2], e1 = top_e[tk * 2 + 1];
        if (e0 == e) { m = 1; w = top_w[tk * 2]; }
        else if (e1 == e) { m = 1; w = top_w[tk * 2 + 1]; }
        sc[tid] = m;
        __syncthreads();
        for (int s = 1; s < 256; s <<= 1) {
            int v = (tid >= s) ? sc[tid - s] : 0;
            __syncthreads();
            sc[tid] += v;
            __syncthreads();
        }
        if (m) { int pos = base + sc[tid] - 1; pair_token[pos] = tk; pair_w[pos] = w; }
        base += sc[255];
        __syncthreads();
    }
    int cnt = counts[e];
    int padded = (cnt + BM - 1) & ~(BM - 1);
    for (int r = cnt + tid; r < padded; r += 256) {
        pair_token[offs[e] + r] = 0;
        pair_w[offs[e] + r] = 0.f;
    }
}

// ---------------- GEMM1: h = silu(x@w1) * (x@w3), m97 structure, fp16 MFMA ----------------
__global__ __launch_bounds__(256, 3) void gemm1_kernel(
    const u16* __restrict__ xh, const u16* __restrict__ wcat,
    const int* __restrict__ pair_token, const int* __restrict__ mt_e,
    const int* __restrict__ mt_r0, const int* __restrict__ nmt,
    u16* __restrict__ hb) {
    int mt, by;
    xcd_remap(blockIdx.x, 17, mt, by);     // cluster grid 17 x 8 (by in [0,64))
    if (mt >= *nmt) return;
    const int e = mt_e[mt], row0 = mt_r0[mt];
    const int tid = threadIdx.x, lane = tid & 63, wv = tid >> 6;
    const int wm = wv >> 1, wn = wv & 1;

    __shared__ u16 sA[128 * 64];
    __shared__ u16 sB[128 * 64];

    const u16* asrc[4];
    const u16* bsrc[4];
#pragma unroll
    for (int i = 0; i < 4; ++i) {
        int rl = i * 32 + (tid >> 3);
        int kbs = ((tid & 7) * 16) ^ ((rl & 7) << 4);      // byte offset, pre-swizzled
        asrc[i] = xh + (size_t)pair_token[row0 + rl] * HD + (kbs >> 1);
        bsrc[i] = wcat + (size_t)e * 2 * ID * HD + (size_t)(by * 128 + rl) * HD + (kbs >> 1);
    }

    f32x4 acc[4][4];
#pragma unroll
    for (int a = 0; a < 4; ++a)
#pragma unroll
        for (int b = 0; b < 4; ++b) acc[a][b] = (f32x4)0.f;

    for (int kt = 0; kt < HD / 64; ++kt) {
#pragma unroll
        for (int i = 0; i < 4; ++i) {
            __builtin_amdgcn_global_load_lds(
                (const __attribute__((address_space(1))) void*)asrc[i],
                (__attribute__((address_space(3))) void*)(sA + i * 2048 + wv * 512), 16, 0, 0);
            asrc[i] += 64;
        }
#pragma unroll
        for (int i = 0; i < 4; ++i) {
            __builtin_amdgcn_global_load_lds(
                (const __attribute__((address_space(1))) void*)bsrc[i],
                (__attribute__((address_space(3))) void*)(sB + i * 2048 + wv * 512), 16, 0, 0);
            bsrc[i] += 64;
        }
        __syncthreads();
#pragma unroll
        for (int ks = 0; ks < 2; ++ks) {
            i32x4 a[4], b[4];
#pragma unroll
            for (int mf = 0; mf < 4; ++mf) {
                int rr = wm * 64 + mf * 16 + (lane & 15);
                int lb = ((lane >> 4) * 16 + ks * 64) ^ ((rr & 7) << 4);
                a[mf] = *(const i32x4*)((const char*)sA + rr * 128 + lb);
            }
#pragma unroll
            for (int nf = 0; nf < 4; ++nf) {
                int nn = wn * 64 + nf * 16 + (lane & 15);
                int lb = ((lane >> 4) * 16 + ks * 64) ^ ((nn & 7) << 4);
                b[nf] = *(const i32x4*)((const char*)sB + nn * 128 + lb);
            }
#pragma unroll
            for (int nf = 0; nf < 4; ++nf)
#pragma unroll
                for (int mf = 0; mf < 4; ++mf)
                    asm("v_mfma_f32_16x16x32_f16 %0, %1, %2, %0" : "+v"(acc[mf][nf]) : "v"(a[mf]), "v"(b[nf]));
        }
        __syncthreads();
    }

    // epilogue: nf even = gate, nf odd = up; real col = by*64 + wn*32 + np*16 + (lane&15)
#pragma unroll
    for (int mf = 0; mf < 4; ++mf) {
#pragma unroll
        for (int j = 0; j < 4; ++j) {
            size_t rr = (size_t)row0 + wm * 64 + mf * 16 + (lane >> 4) * 4 + j;
            u16* hp_ = hb + rr * ID + by * 64 + wn * 32 + (lane & 15);
#pragma unroll
            for (int np = 0; np < 2; ++np) {
                float g = acc[mf][2 * np][j], u = acc[mf][2 * np + 1][j];
                float s = g / (1.f + expf(-g));
                hp_[np * 16] = f2h(s * u);
            }
        }
    }
}

// ---------------- GEMM2: out += (h@w2t) * weight (atomicAdd fp32) ----------------
__global__ __launch_bounds__(256, 3) void gemm2_kernel(
    const u16* __restrict__ hb, const u16* __restrict__ w2t,
    const int* __restrict__ pair_token, const float* __restrict__ pair_w,
    const int* __restrict__ mt_e, const int* __restrict__ mt_r0, const int* __restrict__ nmt,
    float* __restrict__ out) {
    int mt, by;
    xcd_remap(blockIdx.x, 20, mt, by);     // cluster grid 20 x 2, mt padded to 160, by in [0,16)
    if (mt >= *nmt) return;
    const int e = mt_e[mt], row0 = mt_r0[mt];
    const int tid = threadIdx.x, lane = tid & 63, wv = tid >> 6;
    const int wm = wv >> 1, wn = wv & 1;

    __shared__ u16 sA[128 * 64];
    __shared__ u16 sB[128 * 64];

    const u16* asrc[4];
    const u16* bsrc[4];
#pragma unroll
    for (int i = 0; i < 4; ++i) {
        int rl = i * 32 + (tid >> 3);
        int kbs = ((tid & 7) * 16) ^ ((rl & 7) << 4);
        asrc[i] = hb + (size_t)(row0 + rl) * ID + (kbs >> 1);
        bsrc[i] = w2t + (size_t)e * HD * ID + (size_t)(by * 128 + rl) * ID + (kbs >> 1);
    }

    f32x4 acc[4][4];
#pragma unroll
    for (int a = 0; a < 4; ++a)
#pragma unroll
        for (int b = 0; b < 4; ++b) acc[a][b] = (f32x4)0.f;

    for (int kt = 0; kt < ID / 64; ++kt) {
#pragma unroll
        for (int i = 0; i < 4; ++i) {
            __builtin_amdgcn_global_load_lds(
                (const __attribute__((address_space(1))) void*)asrc[i],
                (__attribute__((address_space(3))) void*)(sA + i * 2048 + wv * 512), 16, 0, 0);
            asrc[i] += 64;
        }
#pragma unroll
        for (int i = 0; i < 4; ++i) {
            __builtin_amdgcn_global_load_lds(
                (const __attribute__((address_space(1))) void*)bsrc[i],
                (__attribute__((address_space(3))) void*)(sB + i * 2048 + wv * 512), 16, 0, 0);
            bsrc[i] += 64;
        }
        __syncthreads();
#pragma unroll
        for (int ks = 0; ks < 2; ++ks) {
            i32x4 a[4], b[4];
#pragma unroll
            for (int mf = 0; mf < 4; ++mf) {
                int rr = wm * 64 + mf * 16 + (lane & 15);
                int lb = ((lane >> 4) * 16 + ks * 64) ^ ((rr & 7) << 4);
                a[mf] = *(const i32x4*)((const char*)sA + rr * 128 + lb);
            }
#pragma unroll
            for (int nf = 0; nf < 4; ++nf) {
                int nn = wn * 64 + nf * 16 + (lane & 15);
                int lb = ((lane >> 4) * 16 + ks * 64) ^ ((nn & 7) << 4);
                b[nf] = *(const i32x4*)((const char*)sB + nn * 128 + lb);
            }
#pragma unroll
            for (int nf = 0; nf < 4; ++nf)
#pragma unroll
                for (int mf = 0; mf < 4; ++mf)
                    asm("v_mfma_f32_16x16x32_f16 %0, %1, %2, %0" : "+v"(acc[mf][nf]) : "v"(a[mf]), "v"(b[nf]));
        }
        __syncthreads();
    }

#pragma unroll
    for (int mf = 0; mf < 4; ++mf) {
#pragma unroll
        for (int j = 0; j < 4; ++j) {
            int rr = row0 + wm * 64 + mf * 16 + (lane >> 4) * 4 + j;
            int tok = pair_token[rr];
            float wt = pair_w[rr];
            float* op = out + (size_t)tok * HD + by * 128 + wn * 64 + (lane & 15);
#pragma unroll
            for (int nf = 0; nf < 4; ++nf) {
                atomicAdd(op + nf * 16, acc[mf][nf][j] * wt);
            }
        }
    }
}

extern "C" void kernel_launch(void* const* d_in, const int* in_sizes, int n_in,
                              void* d_out, int out_size, void* d_ws, size_t ws_size,
                              hipStream_t stream) {
    (void)in_sizes; (void)n_in; (void)ws_size;
    const float* x  = (const float*)d_in[0];
    const float* wg = (const float*)d_in[1];
    const float* w1 = (const float*)d_in[2];
    const float* w3 = (const float*)d_in[3];
    const float* w2 = (const float*)d_in[4];
    float* out = (float*)d_out;

    char* ws = (char*)d_ws;
    size_t off = 0;
    auto alloc = [&](size_t bytes) -> void* {
        void* p = ws + off;
        off = (off + bytes + 255) & ~(size_t)255;
        return p;
    };
    u16* xh          = (u16*)alloc((size_t)TOK * HD * 2);
    u16* hb          = (u16*)alloc((size_t)PPAD * ID * 2);
    u16* wcat        = (u16*)alloc((size_t)NE * 2 * ID * HD * 2);  // w13 interleaved fp16
    u16* w2t         = wcat;                                       // aliased: used after gemm1
    int* pair_token  = (int*)alloc((size_t)PPAD * 4);
    float* pair_w    = (float*)alloc((size_t)PPAD * 4);
    int* top_e       = (int*)alloc((size_t)TOK * 2 * 4);
    float* top_w     = (float*)alloc((size_t)TOK * 2 * 4);
    int* counts      = (int*)alloc(64);
    int* offs        = (int*)alloc(64);
    int* mt_e        = (int*)alloc((size_t)MAXMT * 4);
    int* mt_r0       = (int*)alloc((size_t)MAXMT * 4);
    int* nmt         = (int*)alloc(64);

    hipMemsetAsync(out, 0, (size_t)out_size * 4, stream);
    hipMemsetAsync(counts, 0, 64, stream);

    cast_x_kernel<<<TOK * HD / 8 / 256, 256, 0, stream>>>(x, xh);
    router_kernel<<<TOK / 4, 256, 0, stream>>>(x, wg, top_e, top_w, counts);
    offsets_kernel<<<1, 64, 0, stream>>>(counts, offs, mt_e, mt_r0, nmt);
    scatter_kernel<<<NE, 256, 0, stream>>>(top_e, top_w, counts, offs, pair_token, pair_w);
    prep_w13_kernel<<<dim3(HD / 64, ID / 64, NE * 2), 256, 0, stream>>>(w1, w3, wcat);
    // gemm1: 136 mt-tiles x 64 by-blocks, XCD-clustered 1D launch (17x8 cluster grid)
    gemm1_kernel<<<MAXMT * (ID / 64), 256, 0, stream>>>(xh, wcat, pair_token, mt_e, mt_r0, nmt, hb);
    prep_w2_kernel<<<dim3(ID / 64, HD / 64, NE), 256, 0, stream>>>(w2, w2t);  // wcat dead now
    // gemm2: mt padded to 160 x 16 by-blocks, XCD-clustered (20x2 cluster grid)
    gemm2_kernel<<<160 * (HD / 128), 256, 0, stream>>>(hb, w2t, pair_token, pair_w, mt_e, mt_r0, nmt, out);
}

// Round 4
// 1360.654 us; speedup vs baseline: 1.7969x; 1.0243x over previous
//
#include <hip/hip_runtime.h>
#include <hip/hip_bf16.h>
#include <hip/hip_fp16.h>

// ---- problem constants ----
#define TOK 8192      // 4*2048 tokens
#define HD 2048       // hidden
#define ID 4096       // intermediate
#define NE 8          // experts
#define NPAIR (TOK*2) // token-expert pairs (TOPK=2)
#define BM 128
#define MAXMT (NPAIR/BM + NE)   // 136 worst-case M-tiles
#define PPAD (NPAIR + NE*BM)    // 17408 worst-case padded rows

typedef unsigned short u16;
typedef unsigned int u32;
typedef __attribute__((ext_vector_type(4))) float f32x4;
typedef __attribute__((ext_vector_type(4))) int   i32x4;
typedef u16 u16x8 __attribute__((ext_vector_type(8)));
typedef u16 u16x4 __attribute__((ext_vector_type(4)));

__device__ __forceinline__ u16 f2h(float f) {
    __half h = __float2half_rn(f);
    return *reinterpret_cast<u16*>(&h);
}

// XCD-clustered remap: cluster = 8mt x 8by = 64 blocks, all on one XCD
// (p%8 = XCD round-robin). Cluster grid = CGM x CGN, CGM*CGN divisible by 8.
__device__ __forceinline__ void xcd_remap(int p, int CGM, int& mt, int& by) {
    int x = p & 7;          // XCD
    int j = p >> 3;         // sequence within XCD
    int c = j >> 6;         // cluster counter within XCD
    int s = j & 63;         // slot within cluster
    int C = c * 8 + x;      // global cluster id
    int mtc = C % CGM;
    int byc = C / CGM;
    mt = mtc * 8 + (s >> 3);
    by = byc * 8 + (s & 7);
}

// ---------------- cast x fp32 -> fp16 ----------------
__global__ void cast_x_kernel(const float* __restrict__ x, u16* __restrict__ xh) {
    size_t idx = (size_t)blockIdx.x * 256 + threadIdx.x;   // 8 elems each
    const f32x4* p = (const f32x4*)x + idx * 2;
    f32x4 a = p[0], b = p[1];
    u16x8 o;
#pragma unroll
    for (int i = 0; i < 4; ++i) { o[i] = f2h(a[i]); o[4 + i] = f2h(b[i]); }
    *((u16x8*)xh + idx) = o;
}

// ---------------- prep: w1/w3 fp32 [H][I] -> interleaved fp16 wcat [2*I][H] ----------------
// wcat row for w1 col n: ((n>>4)<<5)|(n&15);  for w3: ((n>>4)<<5)|16|(n&15)
__global__ __launch_bounds__(256) void prep_w13_kernel(const float* __restrict__ w1,
                                                       const float* __restrict__ w3,
                                                       u16* __restrict__ wcat) {
    __shared__ u16 tile[64][68];   // [n_local][k_local]
    const int k0 = blockIdx.x * 64, n0 = blockIdx.y * 64;
    const int e = blockIdx.z >> 1, which = blockIdx.z & 1;
    const float* src = (which ? w3 : w1) + (size_t)e * HD * ID;
    u16* dst = wcat + (size_t)e * 2 * ID * HD;
    const int tid = threadIdx.x, r = tid >> 4, c4 = (tid & 15) * 4;
#pragma unroll
    for (int i = 0; i < 4; ++i) {
        int k = k0 + r + 16 * i;
        f32x4 v = *(const f32x4*)(src + (size_t)k * ID + n0 + c4);
#pragma unroll
        for (int j = 0; j < 4; ++j) tile[c4 + j][r + 16 * i] = f2h(v[j]);
    }
    __syncthreads();
#pragma unroll
    for (int i = 0; i < 4; ++i) {
        int nl = r + 16 * i;
        int n = n0 + nl;
        int wr = ((n >> 4) << 5) | (which << 4) | (n & 15);
        u16x4 o;
#pragma unroll
        for (int j = 0; j < 4; ++j) o[j] = tile[nl][c4 + j];
        *(u16x4*)(dst + (size_t)wr * HD + k0 + c4) = o;
    }
}

// ---------------- prep: w2 fp32 [I][H] -> fp16 w2t [H][I] ----------------
__global__ __launch_bounds__(256) void prep_w2_kernel(const float* __restrict__ w2,
                                                      u16* __restrict__ w2t) {
    __shared__ u16 tile[64][68];
    const int k0 = blockIdx.x * 64, n0 = blockIdx.y * 64;
    const int e = blockIdx.z;
    const float* src = w2 + (size_t)e * ID * HD;
    u16* dst = w2t + (size_t)e * ID * HD;
    const int tid = threadIdx.x, r = tid >> 4, c4 = (tid & 15) * 4;
#pragma unroll
    for (int i = 0; i < 4; ++i) {
        int k = k0 + r + 16 * i;
        f32x4 v = *(const f32x4*)(src + (size_t)k * HD + n0 + c4);
#pragma unroll
        for (int j = 0; j < 4; ++j) tile[c4 + j][r + 16 * i] = f2h(v[j]);
    }
    __syncthreads();
#pragma unroll
    for (int i = 0; i < 4; ++i) {
        int nl = r + 16 * i;
        u16x4 o;
#pragma unroll
        for (int j = 0; j < 4; ++j) o[j] = tile[nl][c4 + j];
        *(u16x4*)(dst + (size_t)(n0 + nl) * ID + k0 + c4) = o;
    }
}

// ---------------- router: fp32 logits, softcap, softmax, top2 ----------------
__global__ void router_kernel(const float* __restrict__ x, const float* __restrict__ wg,
                              int* __restrict__ top_e, float* __restrict__ top_w,
                              int* __restrict__ counts) {
    int t = blockIdx.x * 4 + (threadIdx.x >> 6);
    int l = threadIdx.x & 63;
    const float* xr = x + (size_t)t * HD;
    float acc[NE];
#pragma unroll
    for (int e = 0; e < NE; ++e) acc[e] = 0.f;
    for (int h0 = 0; h0 < HD; h0 += 64) {
        int h = h0 + l;
        float xv = xr[h];
        const f32x4* wr = (const f32x4*)(wg + (size_t)h * NE);
        f32x4 w0 = wr[0], w1v = wr[1];
#pragma unroll
        for (int i = 0; i < 4; ++i) { acc[i] += xv * w0[i]; acc[4 + i] += xv * w1v[i]; }
    }
#pragma unroll
    for (int e = 0; e < NE; ++e) {
        float v = acc[e];
        for (int s = 32; s >= 1; s >>= 1) v += __shfl_xor(v, s);
        acc[e] = v;
    }
    if (l == 0) {
        float li[NE], mx = -1e30f;
#pragma unroll
        for (int e = 0; e < NE; ++e) { li[e] = 30.f * tanhf(acc[e] * (1.f / 30.f)); mx = fmaxf(mx, li[e]); }
        float p[NE], se = 0.f;
#pragma unroll
        for (int e = 0; e < NE; ++e) { p[e] = expf(li[e] - mx); se += p[e]; }
        float inv = 1.f / se;
        int i1 = 0; float p1 = p[0];
#pragma unroll
        for (int e = 1; e < NE; ++e) if (p[e] > p1) { p1 = p[e]; i1 = e; }
        int i2 = -1; float p2 = -1e30f;
#pragma unroll
        for (int e = 0; e < NE; ++e) if (e != i1 && p[e] > p2) { p2 = p[e]; i2 = e; }
        top_e[t * 2] = i1; top_e[t * 2 + 1] = i2;
        top_w[t * 2] = p1 * inv; top_w[t * 2 + 1] = p2 * inv;
        atomicAdd(&counts[i1], 1); atomicAdd(&counts[i2], 1);
    }
}

// ---------------- offsets + M-tile table (1 thread) ----------------
__global__ void offsets_kernel(const int* __restrict__ counts, int* __restrict__ offs,
                               int* __restrict__ mt_e, int* __restrict__ mt_r0,
                               int* __restrict__ nmt) {
    if (threadIdx.x != 0) return;
    int off = 0, n = 0;
    for (int e = 0; e < NE; ++e) {
        offs[e] = off;
        int c = counts[e];
        int nt = (c + BM - 1) >> 7;
        for (int j = 0; j < nt; ++j) { mt_e[n] = e; mt_r0[n] = off + j * BM; ++n; }
        off += nt * BM;
    }
    offs[NE] = off;
    *nmt = n;
}

// ---------------- deterministic per-expert compaction ----------------
// pair_tok2[pos] = token*2 + slot (slot: 0 = primary expert, 1 = secondary); pads = -2
__global__ void scatter_kernel(const int* __restrict__ top_e, const float* __restrict__ top_w,
                               const int* __restrict__ counts, const int* __restrict__ offs,
                               int* __restrict__ pair_tok2, float* __restrict__ pair_w) {
    const int e = blockIdx.x;
    const int tid = threadIdx.x;
    __shared__ int sc[256];
    int base = offs[e];
    for (int start = 0; start < TOK; start += 256) {
        int tk = start + tid;
        int m = 0; float w = 0.f; int slot = 0;
        int e0 = top_e[tk * 2], e1 = top_e[tk * 2 + 1];
        if (e0 == e) { m = 1; w = top_w[tk * 2]; slot = 0; }
        else if (e1 == e) { m = 1; w = top_w[tk * 2 + 1]; slot = 1; }
        sc[tid] = m;
        __syncthreads();
        for (int s = 1; s < 256; s <<= 1) {
            int v = (tid >= s) ? sc[tid - s] : 0;
            __syncthreads();
            sc[tid] += v;
            __syncthreads();
        }
        if (m) { int pos = base + sc[tid] - 1; pair_tok2[pos] = tk * 2 + slot; pair_w[pos] = w; }
        base += sc[255];
        __syncthreads();
    }
    int cnt = counts[e];
    int padded = (cnt + BM - 1) & ~(BM - 1);
    for (int r = cnt + tid; r < padded; r += 256) {
        pair_tok2[offs[e] + r] = -2;
        pair_w[offs[e] + r] = 0.f;
    }
}

// ---------------- GEMM1: h = silu(x@w1) * (x@w3), m97 structure, fp16 MFMA ----------------
__global__ __launch_bounds__(256, 3) void gemm1_kernel(
    const u16* __restrict__ xh, const u16* __restrict__ wcat,
    const int* __restrict__ pair_tok2, const int* __restrict__ mt_e,
    const int* __restrict__ mt_r0, const int* __restrict__ nmt,
    u16* __restrict__ hb) {
    int mt, by;
    xcd_remap(blockIdx.x, 17, mt, by);     // cluster grid 17 x 8 (by in [0,64))
    if (mt >= *nmt) return;
    const int e = mt_e[mt], row0 = mt_r0[mt];
    const int tid = threadIdx.x, lane = tid & 63, wv = tid >> 6;
    const int wm = wv >> 1, wn = wv & 1;

    __shared__ u16 sA[128 * 64];
    __shared__ u16 sB[128 * 64];

    const u16* asrc[4];
    const u16* bsrc[4];
#pragma unroll
    for (int i = 0; i < 4; ++i) {
        int rl = i * 32 + (tid >> 3);
        int kbs = ((tid & 7) * 16) ^ ((rl & 7) << 4);      // byte offset, pre-swizzled
        int pt2 = pair_tok2[row0 + rl];
        int tok = pt2 < 0 ? 0 : (pt2 >> 1);
        asrc[i] = xh + (size_t)tok * HD + (kbs >> 1);
        bsrc[i] = wcat + (size_t)e * 2 * ID * HD + (size_t)(by * 128 + rl) * HD + (kbs >> 1);
    }

    f32x4 acc[4][4];
#pragma unroll
    for (int a = 0; a < 4; ++a)
#pragma unroll
        for (int b = 0; b < 4; ++b) acc[a][b] = (f32x4)0.f;

    for (int kt = 0; kt < HD / 64; ++kt) {
#pragma unroll
        for (int i = 0; i < 4; ++i) {
            __builtin_amdgcn_global_load_lds(
                (const __attribute__((address_space(1))) void*)asrc[i],
                (__attribute__((address_space(3))) void*)(sA + i * 2048 + wv * 512), 16, 0, 0);
            asrc[i] += 64;
        }
#pragma unroll
        for (int i = 0; i < 4; ++i) {
            __builtin_amdgcn_global_load_lds(
                (const __attribute__((address_space(1))) void*)bsrc[i],
                (__attribute__((address_space(3))) void*)(sB + i * 2048 + wv * 512), 16, 0, 0);
            bsrc[i] += 64;
        }
        __syncthreads();
#pragma unroll
        for (int ks = 0; ks < 2; ++ks) {
            i32x4 a[4], b[4];
#pragma unroll
            for (int mf = 0; mf < 4; ++mf) {
                int rr = wm * 64 + mf * 16 + (lane & 15);
                int lb = ((lane >> 4) * 16 + ks * 64) ^ ((rr & 7) << 4);
                a[mf] = *(const i32x4*)((const char*)sA + rr * 128 + lb);
            }
#pragma unroll
            for (int nf = 0; nf < 4; ++nf) {
                int nn = wn * 64 + nf * 16 + (lane & 15);
                int lb = ((lane >> 4) * 16 + ks * 64) ^ ((nn & 7) << 4);
                b[nf] = *(const i32x4*)((const char*)sB + nn * 128 + lb);
            }
#pragma unroll
            for (int nf = 0; nf < 4; ++nf)
#pragma unroll
                for (int mf = 0; mf < 4; ++mf)
                    asm("v_mfma_f32_16x16x32_f16 %0, %1, %2, %0" : "+v"(acc[mf][nf]) : "v"(a[mf]), "v"(b[nf]));
        }
        __syncthreads();
    }

    // epilogue: nf even = gate, nf odd = up; real col = by*64 + wn*32 + np*16 + (lane&15)
#pragma unroll
    for (int mf = 0; mf < 4; ++mf) {
#pragma unroll
        for (int j = 0; j < 4; ++j) {
            size_t rr = (size_t)row0 + wm * 64 + mf * 16 + (lane >> 4) * 4 + j;
            u16* hp_ = hb + rr * ID + by * 64 + wn * 32 + (lane & 15);
#pragma unroll
            for (int np = 0; np < 2; ++np) {
                float g = acc[mf][2 * np][j], u = acc[mf][2 * np + 1][j];
                float s = g / (1.f + expf(-g));
                hp_[np * 16] = f2h(s * u);
            }
        }
    }
}

// ---------------- GEMM2: ob[tok*2+slot] = (h@w2t) * weight (plain stores) ----------------
__global__ __launch_bounds__(256, 3) void gemm2_kernel(
    const u16* __restrict__ hb, const u16* __restrict__ w2t,
    const int* __restrict__ pair_tok2, const float* __restrict__ pair_w,
    const int* __restrict__ mt_e, const int* __restrict__ mt_r0, const int* __restrict__ nmt,
    float* __restrict__ ob) {
    int mt, by;
    xcd_remap(blockIdx.x, 20, mt, by);     // cluster grid 20 x 2, mt padded to 160, by in [0,16)
    if (mt >= *nmt) return;
    const int e = mt_e[mt], row0 = mt_r0[mt];
    const int tid = threadIdx.x, lane = tid & 63, wv = tid >> 6;
    const int wm = wv >> 1, wn = wv & 1;

    __shared__ u16 sA[128 * 64];
    __shared__ u16 sB[128 * 64];

    const u16* asrc[4];
    const u16* bsrc[4];
#pragma unroll
    for (int i = 0; i < 4; ++i) {
        int rl = i * 32 + (tid >> 3);
        int kbs = ((tid & 7) * 16) ^ ((rl & 7) << 4);
        asrc[i] = hb + (size_t)(row0 + rl) * ID + (kbs >> 1);
        bsrc[i] = w2t + (size_t)e * HD * ID + (size_t)(by * 128 + rl) * ID + (kbs >> 1);
    }

    f32x4 acc[4][4];
#pragma unroll
    for (int a = 0; a < 4; ++a)
#pragma unroll
        for (int b = 0; b < 4; ++b) acc[a][b] = (f32x4)0.f;

    for (int kt = 0; kt < ID / 64; ++kt) {
#pragma unroll
        for (int i = 0; i < 4; ++i) {
            __builtin_amdgcn_global_load_lds(
                (const __attribute__((address_space(1))) void*)asrc[i],
                (__attribute__((address_space(3))) void*)(sA + i * 2048 + wv * 512), 16, 0, 0);
            asrc[i] += 64;
        }
#pragma unroll
        for (int i = 0; i < 4; ++i) {
            __builtin_amdgcn_global_load_lds(
                (const __attribute__((address_space(1))) void*)bsrc[i],
                (__attribute__((address_space(3))) void*)(sB + i * 2048 + wv * 512), 16, 0, 0);
            bsrc[i] += 64;
        }
        __syncthreads();
#pragma unroll
        for (int ks = 0; ks < 2; ++ks) {
            i32x4 a[4], b[4];
#pragma unroll
            for (int mf = 0; mf < 4; ++mf) {
                int rr = wm * 64 + mf * 16 + (lane & 15);
                int lb = ((lane >> 4) * 16 + ks * 64) ^ ((rr & 7) << 4);
                a[mf] = *(const i32x4*)((const char*)sA + rr * 128 + lb);
            }
#pragma unroll
            for (int nf = 0; nf < 4; ++nf) {
                int nn = wn * 64 + nf * 16 + (lane & 15);
                int lb = ((lane >> 4) * 16 + ks * 64) ^ ((nn & 7) << 4);
                b[nf] = *(const i32x4*)((const char*)sB + nn * 128 + lb);
            }
#pragma unroll
            for (int nf = 0; nf < 4; ++nf)
#pragma unroll
                for (int mf = 0; mf < 4; ++mf)
                    asm("v_mfma_f32_16x16x32_f16 %0, %1, %2, %0" : "+v"(acc[mf][nf]) : "v"(a[mf]), "v"(b[nf]));
        }
        __syncthreads();
    }

#pragma unroll
    for (int mf = 0; mf < 4; ++mf) {
#pragma unroll
        for (int j = 0; j < 4; ++j) {
            int rr = row0 + wm * 64 + mf * 16 + (lane >> 4) * 4 + j;
            int pt2 = pair_tok2[rr];
            float wt = pair_w[rr];
            if (pt2 >= 0) {
                float* op = ob + (size_t)pt2 * HD + by * 128 + wn * 64 + (lane & 15);
#pragma unroll
                for (int nf = 0; nf < 4; ++nf) {
                    op[nf * 16] = acc[mf][nf][j] * wt;
                }
            }
        }
    }
}

// ---------------- combine: out[t] = ob[2t] + ob[2t+1] ----------------
__global__ __launch_bounds__(256) void combine_kernel(const float* __restrict__ ob,
                                                      float* __restrict__ out) {
    int t = blockIdx.x;
    const f32x4* r0 = (const f32x4*)(ob + (size_t)(2 * t) * HD);
    const f32x4* r1 = (const f32x4*)(ob + (size_t)(2 * t + 1) * HD);
    f32x4* o = (f32x4*)(out + (size_t)t * HD);
#pragma unroll
    for (int i = 0; i < 2; ++i) {
        int idx = threadIdx.x + i * 256;
        o[idx] = r0[idx] + r1[idx];
    }
}

extern "C" void kernel_launch(void* const* d_in, const int* in_sizes, int n_in,
                              void* d_out, int out_size, void* d_ws, size_t ws_size,
                              hipStream_t stream) {
    (void)in_sizes; (void)n_in; (void)ws_size; (void)out_size;
    const float* x  = (const float*)d_in[0];
    const float* wg = (const float*)d_in[1];
    const float* w1 = (const float*)d_in[2];
    const float* w3 = (const float*)d_in[3];
    const float* w2 = (const float*)d_in[4];
    float* out = (float*)d_out;

    char* ws = (char*)d_ws;
    size_t off = 0;
    auto alloc = [&](size_t bytes) -> void* {
        void* p = ws + off;
        off = (off + bytes + 255) & ~(size_t)255;
        return p;
    };
    u16* xh          = (u16*)alloc((size_t)TOK * HD * 2);
    u16* hb          = (u16*)alloc((size_t)PPAD * ID * 2);
    u16* wcat        = (u16*)alloc((size_t)NE * 2 * ID * HD * 2);  // w13 fp16 (gemm1 phase)
    // after gemm1: first half of wcat (134.2 MB) becomes ob [2*TOK][HD] fp32 (exact fit);
    // second half becomes w2t [E][H][I] fp16.
    float* ob        = (float*)wcat;
    u16* w2t         = wcat + (size_t)NE * ID * HD;
    int* pair_tok2   = (int*)alloc((size_t)PPAD * 4);
    float* pair_w    = (float*)alloc((size_t)PPAD * 4);
    int* top_e       = (int*)alloc((size_t)TOK * 2 * 4);
    float* top_w     = (float*)alloc((size_t)TOK * 2 * 4);
    int* counts      = (int*)alloc(64);
    int* offs        = (int*)alloc(64);
    int* mt_e        = (int*)alloc((size_t)MAXMT * 4);
    int* mt_r0       = (int*)alloc((size_t)MAXMT * 4);
    int* nmt         = (int*)alloc(64);

    hipMemsetAsync(counts, 0, 64, stream);

    cast_x_kernel<<<TOK * HD / 8 / 256, 256, 0, stream>>>(x, xh);
    router_kernel<<<TOK / 4, 256, 0, stream>>>(x, wg, top_e, top_w, counts);
    offsets_kernel<<<1, 64, 0, stream>>>(counts, offs, mt_e, mt_r0, nmt);
    scatter_kernel<<<NE, 256, 0, stream>>>(top_e, top_w, counts, offs, pair_tok2, pair_w);
    prep_w13_kernel<<<dim3(HD / 64, ID / 64, NE * 2), 256, 0, stream>>>(w1, w3, wcat);
    // gemm1: 136 mt-tiles x 64 by-blocks, XCD-clustered 1D launch (17x8 cluster grid)
    gemm1_kernel<<<MAXMT * (ID / 64), 256, 0, stream>>>(xh, wcat, pair_tok2, mt_e, mt_r0, nmt, hb);
    prep_w2_kernel<<<dim3(ID / 64, HD / 64, NE), 256, 0, stream>>>(w2, w2t);  // into wcat 2nd half
    // gemm2: mt padded to 160 x 16 by-blocks, XCD-clustered (20x2 cluster grid)
    gemm2_kernel<<<160 * (HD / 128), 256, 0, stream>>>(hb, w2t, pair_tok2, pair_w, mt_e, mt_r0, nmt, ob);
    combine_kernel<<<TOK, 256, 0, stream>>>(ob, out);
}